// Round 2
// baseline (874.067 us; speedup 1.0000x reference)
//
#include <hip/hip_runtime.h>
#include <hip/hip_bf16.h>
#include <cmath>

#define N_NODESC 20000
#define E_RAW    320000
#define E_TOTC   340000   // + self loops
#define HEADSC   4
#define FC       256      // HEADS*HID
#define NEG_SLOPE 0.2f

// Order-invariant float atomic max via int/uint monotone encoding.
__device__ __forceinline__ void atomicMaxF(float* addr, float val) {
  if (val >= 0.f) atomicMax((int*)addr, __float_as_int(val));
  else            atomicMin((unsigned int*)addr, (unsigned int)__float_as_int(val));
}

// ---------------- GEMM: out[N,256] = A[N,K] @ W[K,256] (f32) ----------------
template<int K, int ROWS>
__global__ void gemm_kernel(const float* __restrict__ A, const float* __restrict__ W,
                            float* __restrict__ out) {
  __shared__ float xs[ROWS][K];
  const int m  = threadIdx.x;           // 256 threads = one output column each
  const int n0 = blockIdx.x * ROWS;
  for (int idx = threadIdx.x; idx < ROWS * K; idx += 256) {
    int r = idx / K, k = idx - r * K;
    int n = n0 + r;
    xs[r][k] = (n < N_NODESC) ? A[(long)n * K + k] : 0.f;
  }
  __syncthreads();
  float acc[ROWS];
#pragma unroll
  for (int r = 0; r < ROWS; ++r) acc[r] = 0.f;
  for (int k = 0; k < K; ++k) {
    float w = W[k * FC + m];
#pragma unroll
    for (int r = 0; r < ROWS; ++r) acc[r] = fmaf(xs[r][k], w, acc[r]);
  }
  for (int r = 0; r < ROWS; ++r) {
    int n = n0 + r;
    if (n < N_NODESC) out[(long)n * FC + m] = acc[r];
  }
}

// ------------- per-node alpha_src/alpha_dst: wave(64)=one head -------------
__global__ void alpha_kernel(const float* __restrict__ hfeat,
                             const float* __restrict__ a_src, const float* __restrict__ a_dst,
                             float* __restrict__ as, float* __restrict__ ad) {
  const int n = blockIdx.x;
  const int t = threadIdx.x;            // 256: head = t>>6, c = t&63
  float hv = hfeat[(long)n * FC + t];
  float vs = hv * a_src[t];
  float vd = hv * a_dst[t];
  for (int off = 32; off; off >>= 1) {
    vs += __shfl_down(vs, off, 64);
    vd += __shfl_down(vd, off, 64);
  }
  if ((t & 63) == 0) {
    as[n * HEADSC + (t >> 6)] = vs;
    ad[n * HEADSC + (t >> 6)] = vd;
  }
}

// ------------- layer3 projection: h3[n] = act[n,:] . W3, + alphas ----------
__global__ void gemm3_kernel(const float* __restrict__ A, const float* __restrict__ W3,
                             const float* __restrict__ asc, const float* __restrict__ adc,
                             float* __restrict__ h3, float* __restrict__ as,
                             float* __restrict__ ad) {
  const int n = blockIdx.x;
  const int t = threadIdx.x;            // 256
  float v = A[(long)n * FC + t] * W3[t];
  for (int off = 32; off; off >>= 1) v += __shfl_down(v, off, 64);
  __shared__ float red[4];
  if ((t & 63) == 0) red[t >> 6] = v;
  __syncthreads();
  if (t == 0) {
    float s = red[0] + red[1] + red[2] + red[3];
    h3[n] = s;
    as[n] = s * asc[0];
    ad[n] = s * adc[0];
  }
}

// ------------------------------- init --------------------------------------
__global__ void init_kernel(float* __restrict__ agg, float* __restrict__ denom,
                            float* __restrict__ emax, int nAgg, int nH) {
  const int i = blockIdx.x * 256 + threadIdx.x;
  if (i < nAgg) agg[i] = 0.f;
  if (i < nH) { denom[i] = 0.f; emax[i] = -INFINITY; }
}

// ------------------------- edge pass 1: e + segment max --------------------
template<int H>
__global__ void edge_pass1(const int* __restrict__ ei,
                           const float* __restrict__ as, const float* __restrict__ ad,
                           float* __restrict__ ebuf, float* __restrict__ emax) {
  const int i = blockIdx.x * 256 + threadIdx.x;
  if (i >= E_TOTC * H) return;
  const int e = i / H, h = i - e * H;
  int s, d;
  if (e < E_RAW) { s = ei[e]; d = ei[E_RAW + e]; }
  else           { s = d = e - E_RAW; }
  float v = as[s * H + h] + ad[d * H + h];
  v = v > 0.f ? v : NEG_SLOPE * v;
  ebuf[i] = v;
  atomicMaxF(&emax[d * H + h], v);
}

// ------------------------- edge pass 2: exp + denom ------------------------
template<int H>
__global__ void edge_pass2(const int* __restrict__ ei, const float* __restrict__ emax,
                           float* __restrict__ ebuf, float* __restrict__ denom) {
  const int i = blockIdx.x * 256 + threadIdx.x;
  if (i >= E_TOTC * H) return;
  const int e = i / H, h = i - e * H;
  int d;
  if (e < E_RAW) d = ei[E_RAW + e];
  else           d = e - E_RAW;
  float ex = expf(ebuf[i] - emax[d * H + h]);
  ebuf[i] = ex;
  atomicAdd(&denom[d * H + h], ex);
}

// ----------------- edge pass 3: scatter weighted messages ------------------
__global__ void edge_pass3(const int* __restrict__ ei, const float* __restrict__ ebuf,
                           const float* __restrict__ hfeat, float* __restrict__ agg) {
  const int e = blockIdx.x;             // one 256-thread block per edge
  const int t = threadIdx.x;            // channel h*64+c
  int s, d;
  if (e < E_RAW) { s = ei[e]; d = ei[E_RAW + e]; }
  else           { s = d = e - E_RAW; }
  float w = ebuf[e * HEADSC + (t >> 6)];
  atomicAdd(&agg[(long)d * FC + t], w * hfeat[(long)s * FC + t]);
}

__global__ void edge_pass3_s(const int* __restrict__ ei, const float* __restrict__ ebuf,
                             const float* __restrict__ h3, float* __restrict__ agg) {
  const int e = blockIdx.x * 256 + threadIdx.x;
  if (e >= E_TOTC) return;
  int s, d;
  if (e < E_RAW) { s = ei[e]; d = ei[E_RAW + e]; }
  else           { s = d = e - E_RAW; }
  atomicAdd(&agg[d], ebuf[e] * h3[s]);
}

// --------------------- epilogues: normalize + bias (+ELU) ------------------
__global__ void epilogue_elu(const float* __restrict__ agg, const float* __restrict__ denom,
                             const float* __restrict__ b, float* __restrict__ actout) {
  const int i = blockIdx.x * 256 + threadIdx.x;
  if (i >= N_NODESC * FC) return;
  const int n = i >> 8, hc = i & 255, h = hc >> 6;
  float v = agg[i] / denom[n * HEADSC + h] + b[hc];
  v = v > 0.f ? v : expm1f(v);
  actout[i] = v;
}

__global__ void epilogue3(const float* __restrict__ agg, const float* __restrict__ denom,
                          const float* __restrict__ b3, float* __restrict__ out) {
  const int n = blockIdx.x * 256 + threadIdx.x;
  if (n >= N_NODESC) return;
  out[n] = agg[n] / denom[n] + b3[0];
}

extern "C" void kernel_launch(void* const* d_in, const int* in_sizes, int n_in,
                              void* d_out, int out_size, void* d_ws, size_t ws_size,
                              hipStream_t stream) {
  const float* x    = (const float*)d_in[0];
  const int*   ei   = (const int*)d_in[1];
  const float* W1   = (const float*)d_in[2];
  const float* as1  = (const float*)d_in[3];
  const float* ad1  = (const float*)d_in[4];
  const float* b1   = (const float*)d_in[5];
  const float* W2   = (const float*)d_in[6];
  const float* as2  = (const float*)d_in[7];
  const float* ad2  = (const float*)d_in[8];
  const float* b2   = (const float*)d_in[9];
  const float* W3   = (const float*)d_in[10];
  const float* as3  = (const float*)d_in[11];
  const float* ad3  = (const float*)d_in[12];
  const float* b3   = (const float*)d_in[13];
  float* out = (float*)d_out;

  float* ws    = (float*)d_ws;
  float* act   = ws;                              // N*256
  float* hfeat = act   + (size_t)N_NODESC * FC;   // N*256
  float* agg   = hfeat + (size_t)N_NODESC * FC;   // N*256
  float* wAs   = agg   + (size_t)N_NODESC * FC;   // N*4
  float* wAd   = wAs   + (size_t)N_NODESC * HEADSC;
  float* emax  = wAd   + (size_t)N_NODESC * HEADSC;
  float* denom = emax  + (size_t)N_NODESC * HEADSC;
  float* ebuf  = denom + (size_t)N_NODESC * HEADSC; // E_TOT*4

  const int gemmGrid  = (N_NODESC + 15) / 16;
  const int nodeF     = N_NODESC * FC;
  const int gridNF    = (nodeF + 255) / 256;
  const int gridE4    = (E_TOTC * 4 + 255) / 256;
  const int gridE1    = (E_TOTC + 255) / 256;
  const int gridN     = (N_NODESC + 255) / 256;

  // ---------------- layer 1 ----------------
  gemm_kernel<128, 16><<<gemmGrid, 256, 0, stream>>>(x, W1, hfeat);
  alpha_kernel<<<N_NODESC, 256, 0, stream>>>(hfeat, as1, ad1, wAs, wAd);
  init_kernel<<<gridNF, 256, 0, stream>>>(agg, denom, emax, nodeF, N_NODESC * HEADSC);
  edge_pass1<4><<<gridE4, 256, 0, stream>>>(ei, wAs, wAd, ebuf, emax);
  edge_pass2<4><<<gridE4, 256, 0, stream>>>(ei, emax, ebuf, denom);
  edge_pass3<<<E_TOTC, 256, 0, stream>>>(ei, ebuf, hfeat, agg);
  epilogue_elu<<<gridNF, 256, 0, stream>>>(agg, denom, b1, act);

  // ---------------- layer 2 ----------------
  gemm_kernel<256, 16><<<gemmGrid, 256, 0, stream>>>(act, W2, hfeat);
  alpha_kernel<<<N_NODESC, 256, 0, stream>>>(hfeat, as2, ad2, wAs, wAd);
  init_kernel<<<gridNF, 256, 0, stream>>>(agg, denom, emax, nodeF, N_NODESC * HEADSC);
  edge_pass1<4><<<gridE4, 256, 0, stream>>>(ei, wAs, wAd, ebuf, emax);
  edge_pass2<4><<<gridE4, 256, 0, stream>>>(ei, emax, ebuf, denom);
  edge_pass3<<<E_TOTC, 256, 0, stream>>>(ei, ebuf, hfeat, agg);
  epilogue_elu<<<gridNF, 256, 0, stream>>>(agg, denom, b2, act);

  // ---------------- layer 3 (heads=1, out=1) ----------------
  gemm3_kernel<<<N_NODESC, 256, 0, stream>>>(act, W3, as3, ad3, hfeat, wAs, wAd);
  init_kernel<<<gridN, 256, 0, stream>>>(agg, denom, emax, N_NODESC, N_NODESC);
  edge_pass1<1><<<gridE1, 256, 0, stream>>>(ei, wAs, wAd, ebuf, emax);
  edge_pass2<1><<<gridE1, 256, 0, stream>>>(ei, emax, ebuf, denom);
  edge_pass3_s<<<gridE1, 256, 0, stream>>>(ei, ebuf, hfeat, agg);
  epilogue3<<<gridN, 256, 0, stream>>>(agg, denom, b3, out);
}

// Round 3
// 413.592 us; speedup vs baseline: 2.1134x; 2.1134x over previous
//
#include <hip/hip_runtime.h>
#include <hip/hip_bf16.h>
#include <cmath>

#define N_NODESC 20000
#define E_RAW    320000
#define E_TOTC   340000   // + self loops
#define HEADSC   4
#define FC       256      // HEADS*HID
#define NEG_SLOPE 0.2f

__device__ __forceinline__ int dstOf(const int* ei, int e) {
  return (e < E_RAW) ? ei[E_RAW + e] : (e - E_RAW);
}
__device__ __forceinline__ int srcOf(const int* ei, int e) {
  return (e < E_RAW) ? ei[e] : (e - E_RAW);
}

// ---------------- GEMM: out[N,256] = A[N,K] @ W[K,256] (f32) ----------------
template<int K, int ROWS>
__global__ void gemm_kernel(const float* __restrict__ A, const float* __restrict__ W,
                            float* __restrict__ out) {
  __shared__ float xs[ROWS][K];
  const int m  = threadIdx.x;           // 256 threads = one output column each
  const int n0 = blockIdx.x * ROWS;
  for (int idx = threadIdx.x; idx < ROWS * K; idx += 256) {
    int r = idx / K, k = idx - r * K;
    int n = n0 + r;
    xs[r][k] = (n < N_NODESC) ? A[(long)n * K + k] : 0.f;
  }
  __syncthreads();
  float acc[ROWS];
#pragma unroll
  for (int r = 0; r < ROWS; ++r) acc[r] = 0.f;
  for (int k = 0; k < K; ++k) {
    float w = W[k * FC + m];
#pragma unroll
    for (int r = 0; r < ROWS; ++r) acc[r] = fmaf(xs[r][k], w, acc[r]);
  }
  for (int r = 0; r < ROWS; ++r) {
    int n = n0 + r;
    if (n < N_NODESC) out[(long)n * FC + m] = acc[r];
  }
}

// ------------- per-node alpha_src/alpha_dst: wave(64)=one head -------------
__global__ void alpha_kernel(const float* __restrict__ hfeat,
                             const float* __restrict__ a_src, const float* __restrict__ a_dst,
                             float* __restrict__ as, float* __restrict__ ad) {
  const int n = blockIdx.x;
  const int t = threadIdx.x;            // 256: head = t>>6, c = t&63
  float hv = hfeat[(long)n * FC + t];
  float vs = hv * a_src[t];
  float vd = hv * a_dst[t];
  for (int off = 32; off; off >>= 1) {
    vs += __shfl_down(vs, off, 64);
    vd += __shfl_down(vd, off, 64);
  }
  if ((t & 63) == 0) {
    as[n * HEADSC + (t >> 6)] = vs;
    ad[n * HEADSC + (t >> 6)] = vd;
  }
}

// ------------- layer3 projection: h3[n] = act[n,:] . W3, + alphas ----------
__global__ void gemm3_kernel(const float* __restrict__ A, const float* __restrict__ W3,
                             const float* __restrict__ asc, const float* __restrict__ adc,
                             float* __restrict__ h3, float* __restrict__ as,
                             float* __restrict__ ad) {
  const int n = blockIdx.x;
  const int t = threadIdx.x;            // 256
  float v = A[(long)n * FC + t] * W3[t];
  for (int off = 32; off; off >>= 1) v += __shfl_down(v, off, 64);
  __shared__ float red[4];
  if ((t & 63) == 0) red[t >> 6] = v;
  __syncthreads();
  if (t == 0) {
    float s = red[0] + red[1] + red[2] + red[3];
    h3[n] = s;
    as[n] = s * asc[0];
    ad[n] = s * adc[0];
  }
}

// ----------------------------- CSR build -----------------------------------
__global__ void zero_deg(int* __restrict__ deg) {
  int i = blockIdx.x * 256 + threadIdx.x;
  if (i < N_NODESC) deg[i] = 0;
}

__global__ void deg_count(const int* __restrict__ ei, int* __restrict__ deg) {
  int e = blockIdx.x * 256 + threadIdx.x;
  if (e >= E_TOTC) return;
  atomicAdd(&deg[dstOf(ei, e)], 1);
}

__global__ void scan_kernel(const int* __restrict__ deg, int* __restrict__ row_ptr,
                            int* __restrict__ cursor) {
  __shared__ int partial[1024];
  const int t = threadIdx.x;                       // 1024 threads, single block
  const int PER = (N_NODESC + 1023) / 1024;        // 20
  const int base = t * PER;
  int s = 0;
  for (int i = 0; i < PER; ++i) {
    int idx = base + i;
    if (idx < N_NODESC) s += deg[idx];
  }
  partial[t] = s;
  __syncthreads();
  for (int off = 1; off < 1024; off <<= 1) {
    int v = (t >= off) ? partial[t - off] : 0;
    __syncthreads();
    partial[t] += v;
    __syncthreads();
  }
  int run = (t == 0) ? 0 : partial[t - 1];
  for (int i = 0; i < PER; ++i) {
    int idx = base + i;
    if (idx < N_NODESC) {
      row_ptr[idx] = run;
      cursor[idx]  = run;
      run += deg[idx];
    }
  }
  if (t == 1023) row_ptr[N_NODESC] = run;          // = E_TOTC
}

__global__ void fill_kernel(const int* __restrict__ ei, int* __restrict__ cursor,
                            int* __restrict__ col_src) {
  int e = blockIdx.x * 256 + threadIdx.x;
  if (e >= E_TOTC) return;
  int d = dstOf(ei, e);
  int pos = atomicAdd(&cursor[d], 1);
  col_src[pos] = srcOf(ei, e);
}

// --------- softmax per (node,head): two CSR passes, no atomics -------------
template<int H>
__global__ void softmax_kernel(const int* __restrict__ row_ptr, const int* __restrict__ col_src,
                               const float* __restrict__ as, const float* __restrict__ ad,
                               float* __restrict__ ebuf, float* __restrict__ denom) {
  const int i = blockIdx.x * 256 + threadIdx.x;    // n*H + h
  if (i >= N_NODESC * H) return;
  const int n = i / H, h = i - n * H;
  const int j0 = row_ptr[n], j1 = row_ptr[n + 1];
  const float adv = ad[n * H + h];
  float m = -INFINITY;
  for (int j = j0; j < j1; ++j) {
    float v = as[col_src[j] * H + h] + adv;
    v = v > 0.f ? v : NEG_SLOPE * v;
    m = fmaxf(m, v);
  }
  float sum = 0.f;
  for (int j = j0; j < j1; ++j) {
    float v = as[col_src[j] * H + h] + adv;
    v = v > 0.f ? v : NEG_SLOPE * v;
    float ex = expf(v - m);
    ebuf[j * H + h] = ex;
    sum += ex;
  }
  denom[n * H + h] = 1.f / sum;
}

// --------- aggregation: one block per dst node, gather + fused epilogue ----
template<bool ELU>
__global__ void agg_kernel(const int* __restrict__ row_ptr, const int* __restrict__ col_src,
                           const float* __restrict__ ebuf, const float* __restrict__ denom,
                           const float* __restrict__ hfeat, const float* __restrict__ b,
                           float* __restrict__ outbuf) {
  const int d = blockIdx.x;
  const int t = threadIdx.x;                       // channel h*64+c
  const int h = t >> 6;
  const int j0 = row_ptr[d], j1 = row_ptr[d + 1];
  float acc = 0.f;
  for (int j = j0; j < j1; ++j) {
    float w = ebuf[j * HEADSC + h];
    int s = col_src[j];
    acc = fmaf(w, hfeat[(long)s * FC + t], acc);
  }
  float v = acc * denom[d * HEADSC + h] + b[t];
  if (ELU) v = v > 0.f ? v : expm1f(v);
  outbuf[(long)d * FC + t] = v;
}

// ------------- layer3 aggregation: wave per node, scalar -------------------
__global__ void agg3_kernel(const int* __restrict__ row_ptr, const int* __restrict__ col_src,
                            const float* __restrict__ ebuf, const float* __restrict__ denom,
                            const float* __restrict__ h3, const float* __restrict__ b3,
                            float* __restrict__ out) {
  const int wv = threadIdx.x >> 6;                 // 4 waves/block
  const int l  = threadIdx.x & 63;
  const int d  = blockIdx.x * 4 + wv;
  if (d >= N_NODESC) return;
  const int j0 = row_ptr[d], j1 = row_ptr[d + 1];
  float acc = 0.f;
  for (int j = j0 + l; j < j1; j += 64)
    acc = fmaf(ebuf[j], h3[col_src[j]], acc);
  for (int off = 32; off; off >>= 1) acc += __shfl_down(acc, off, 64);
  if (l == 0) out[d] = acc * denom[d] + b3[0];
}

extern "C" void kernel_launch(void* const* d_in, const int* in_sizes, int n_in,
                              void* d_out, int out_size, void* d_ws, size_t ws_size,
                              hipStream_t stream) {
  const float* x    = (const float*)d_in[0];
  const int*   ei   = (const int*)d_in[1];
  const float* W1   = (const float*)d_in[2];
  const float* as1  = (const float*)d_in[3];
  const float* ad1  = (const float*)d_in[4];
  const float* b1   = (const float*)d_in[5];
  const float* W2   = (const float*)d_in[6];
  const float* as2  = (const float*)d_in[7];
  const float* ad2  = (const float*)d_in[8];
  const float* b2   = (const float*)d_in[9];
  const float* W3   = (const float*)d_in[10];
  const float* as3  = (const float*)d_in[11];
  const float* ad3  = (const float*)d_in[12];
  const float* b3   = (const float*)d_in[13];
  float* out = (float*)d_out;

  float* ws    = (float*)d_ws;
  float* act   = ws;                              // N*256
  float* hfeat = act   + (size_t)N_NODESC * FC;   // N*256
  float* wAs   = hfeat + (size_t)N_NODESC * FC;   // N*4
  float* wAd   = wAs   + (size_t)N_NODESC * HEADSC;
  float* denom = wAd   + (size_t)N_NODESC * HEADSC;
  float* ebuf  = denom + (size_t)N_NODESC * HEADSC; // E_TOT*4
  float* h3    = ebuf  + (size_t)E_TOTC * HEADSC;   // N
  int*   ibase = (int*)(h3 + N_NODESC);
  int*   deg     = ibase;                 // N
  int*   row_ptr = deg + N_NODESC;        // N+1
  int*   cursor  = row_ptr + N_NODESC + 1;// N
  int*   col_src = cursor + N_NODESC;     // E_TOT

  const int gemmGrid = (N_NODESC + 15) / 16;
  const int gridE    = (E_TOTC + 255) / 256;
  const int gridN    = (N_NODESC + 255) / 256;
  const int gridNH   = (N_NODESC * HEADSC + 255) / 256;

  // ---------------- CSR build (edge_index shared by all layers) ------------
  zero_deg<<<gridN, 256, 0, stream>>>(deg);
  deg_count<<<gridE, 256, 0, stream>>>(ei, deg);
  scan_kernel<<<1, 1024, 0, stream>>>(deg, row_ptr, cursor);
  fill_kernel<<<gridE, 256, 0, stream>>>(ei, cursor, col_src);

  // ---------------- layer 1 ----------------
  gemm_kernel<128, 16><<<gemmGrid, 256, 0, stream>>>(x, W1, hfeat);
  alpha_kernel<<<N_NODESC, 256, 0, stream>>>(hfeat, as1, ad1, wAs, wAd);
  softmax_kernel<HEADSC><<<gridNH, 256, 0, stream>>>(row_ptr, col_src, wAs, wAd, ebuf, denom);
  agg_kernel<true><<<N_NODESC, 256, 0, stream>>>(row_ptr, col_src, ebuf, denom, hfeat, b1, act);

  // ---------------- layer 2 ----------------
  gemm_kernel<256, 16><<<gemmGrid, 256, 0, stream>>>(act, W2, hfeat);
  alpha_kernel<<<N_NODESC, 256, 0, stream>>>(hfeat, as2, ad2, wAs, wAd);
  softmax_kernel<HEADSC><<<gridNH, 256, 0, stream>>>(row_ptr, col_src, wAs, wAd, ebuf, denom);
  agg_kernel<true><<<N_NODESC, 256, 0, stream>>>(row_ptr, col_src, ebuf, denom, hfeat, b2, act);

  // ---------------- layer 3 (heads=1, out=1) ----------------
  gemm3_kernel<<<N_NODESC, 256, 0, stream>>>(act, W3, as3, ad3, h3, wAs, wAd);
  softmax_kernel<1><<<gridN, 256, 0, stream>>>(row_ptr, col_src, wAs, wAd, ebuf, denom);
  agg3_kernel<<<(N_NODESC + 3) / 4, 256, 0, stream>>>(row_ptr, col_src, ebuf, denom, h3, b3, out);
}

// Round 4
// 355.464 us; speedup vs baseline: 2.4589x; 1.1635x over previous
//
#include <hip/hip_runtime.h>
#include <hip/hip_bf16.h>
#include <cmath>

#define N_NODESC 20000
#define E_RAW    320000
#define E_TOTC   340000   // + self loops
#define HEADSC   4
#define FC       256      // HEADS*HID
#define NEG_SLOPE 0.2f

__device__ __forceinline__ int dstOf(const int* ei, int e) {
  return (e < E_RAW) ? ei[E_RAW + e] : (e - E_RAW);
}
__device__ __forceinline__ int srcOf(const int* ei, int e) {
  return (e < E_RAW) ? ei[e] : (e - E_RAW);
}
__device__ __forceinline__ float lrelu(float v) { return v > 0.f ? v : NEG_SLOPE * v; }

// ------- GEMM: out[N,256] = A[N,K] @ W[K,256]; 32 rows/block, 8x4 per thread
template<int K>
__global__ void gemm_kernel(const float* __restrict__ A, const float* __restrict__ W,
                            float* __restrict__ out) {
  __shared__ float xs[32][K];
  const int t  = threadIdx.x;
  const int m  = t & 63;        // base col
  const int rg = t >> 6;        // row group: rows rg*8 .. rg*8+7
  const int n0 = blockIdx.x * 32;   // 20000 % 32 != 0? 20000/32=625 exact
  for (int idx = t; idx < 32 * K; idx += 256) {
    int r = idx / K, k = idx - r * K;
    xs[r][k] = A[(long)(n0 + r) * K + k];
  }
  __syncthreads();
  float acc[8][4];
#pragma unroll
  for (int i = 0; i < 8; ++i)
#pragma unroll
    for (int q = 0; q < 4; ++q) acc[i][q] = 0.f;
  for (int k = 0; k < K; ++k) {
    const float* wr = W + (long)k * FC + m;
    float w0 = wr[0], w1 = wr[64], w2 = wr[128], w3 = wr[192];
#pragma unroll
    for (int i = 0; i < 8; ++i) {
      float a = xs[rg * 8 + i][k];
      acc[i][0] = fmaf(a, w0, acc[i][0]);
      acc[i][1] = fmaf(a, w1, acc[i][1]);
      acc[i][2] = fmaf(a, w2, acc[i][2]);
      acc[i][3] = fmaf(a, w3, acc[i][3]);
    }
  }
#pragma unroll
  for (int i = 0; i < 8; ++i) {
    float* orow = out + (long)(n0 + rg * 8 + i) * FC + m;
#pragma unroll
    for (int q = 0; q < 4; ++q) orow[q * 64] = acc[i][q];
  }
}

// ------------- per-node alpha_src/alpha_dst: wave(64)=one head -------------
__global__ void alpha_kernel(const float* __restrict__ hfeat,
                             const float* __restrict__ a_src, const float* __restrict__ a_dst,
                             float* __restrict__ as, float* __restrict__ ad) {
  const int n = blockIdx.x;
  const int t = threadIdx.x;            // 256: head = t>>6, c = t&63
  float hv = hfeat[(long)n * FC + t];
  float vs = hv * a_src[t];
  float vd = hv * a_dst[t];
  for (int off = 32; off; off >>= 1) {
    vs += __shfl_down(vs, off, 64);
    vd += __shfl_down(vd, off, 64);
  }
  if ((t & 63) == 0) {
    as[n * HEADSC + (t >> 6)] = vs;
    ad[n * HEADSC + (t >> 6)] = vd;
  }
}

// ------------- layer3 projection: h3[n] = act[n,:] . W3, + alphas ----------
__global__ void gemm3_kernel(const float* __restrict__ A, const float* __restrict__ W3,
                             const float* __restrict__ asc, const float* __restrict__ adc,
                             float* __restrict__ h3, float* __restrict__ as,
                             float* __restrict__ ad) {
  const int n = blockIdx.x;
  const int t = threadIdx.x;            // 256
  float v = A[(long)n * FC + t] * W3[t];
  for (int off = 32; off; off >>= 1) v += __shfl_down(v, off, 64);
  __shared__ float red[4];
  if ((t & 63) == 0) red[t >> 6] = v;
  __syncthreads();
  if (t == 0) {
    float s = red[0] + red[1] + red[2] + red[3];
    h3[n] = s;
    as[n] = s * asc[0];
    ad[n] = s * adc[0];
  }
}

// ----------------------------- CSR build -----------------------------------
__global__ void zero_deg(int* __restrict__ deg) {
  int i = blockIdx.x * 256 + threadIdx.x;
  if (i < N_NODESC) deg[i] = 0;
}

__global__ void deg_count(const int* __restrict__ ei, int* __restrict__ deg) {
  int e = blockIdx.x * 256 + threadIdx.x;
  if (e >= E_TOTC) return;
  atomicAdd(&deg[dstOf(ei, e)], 1);
}

__global__ void scan_kernel(const int* __restrict__ deg, int* __restrict__ row_ptr,
                            int* __restrict__ cursor) {
  __shared__ int partial[1024];
  const int t = threadIdx.x;                       // 1024 threads, single block
  const int PER = (N_NODESC + 1023) / 1024;        // 20
  const int base = t * PER;
  int s = 0;
  for (int i = 0; i < PER; ++i) {
    int idx = base + i;
    if (idx < N_NODESC) s += deg[idx];
  }
  partial[t] = s;
  __syncthreads();
  for (int off = 1; off < 1024; off <<= 1) {
    int v = (t >= off) ? partial[t - off] : 0;
    __syncthreads();
    partial[t] += v;
    __syncthreads();
  }
  int run = (t == 0) ? 0 : partial[t - 1];
  for (int i = 0; i < PER; ++i) {
    int idx = base + i;
    if (idx < N_NODESC) {
      row_ptr[idx] = run;
      cursor[idx]  = run;
      run += deg[idx];
    }
  }
  if (t == 1023) row_ptr[N_NODESC] = run;          // = E_TOTC
}

__global__ void fill_kernel(const int* __restrict__ ei, int* __restrict__ cursor,
                            int* __restrict__ col_src) {
  int e = blockIdx.x * 256 + threadIdx.x;
  if (e >= E_TOTC) return;
  int d = dstOf(ei, e);
  int pos = atomicAdd(&cursor[d], 1);
  col_src[pos] = srcOf(ei, e);
}

// --- softmax, H=4: one thread per node, float4 over heads, unroll-4 MLP ---
__global__ void softmax4_kernel(const int* __restrict__ row_ptr, const int* __restrict__ col_src,
                                const float4* __restrict__ as4, const float4* __restrict__ ad4,
                                float4* __restrict__ ebuf4, float4* __restrict__ denom4) {
  const int n = blockIdx.x * 256 + threadIdx.x;
  if (n >= N_NODESC) return;
  const int j0 = row_ptr[n], j1 = row_ptr[n + 1];
  const float4 adv = ad4[n];
  float m0 = -INFINITY, m1 = -INFINITY, m2 = -INFINITY, m3 = -INFINITY;
  int j = j0;
  for (; j + 4 <= j1; j += 4) {
    int s0 = col_src[j], s1 = col_src[j + 1], s2 = col_src[j + 2], s3 = col_src[j + 3];
    float4 a0 = as4[s0], a1 = as4[s1], a2 = as4[s2], a3 = as4[s3];
#pragma unroll
    for (int u = 0; u < 4; ++u) {
      float4 a = u == 0 ? a0 : u == 1 ? a1 : u == 2 ? a2 : a3;
      m0 = fmaxf(m0, lrelu(a.x + adv.x));
      m1 = fmaxf(m1, lrelu(a.y + adv.y));
      m2 = fmaxf(m2, lrelu(a.z + adv.z));
      m3 = fmaxf(m3, lrelu(a.w + adv.w));
    }
  }
  for (; j < j1; ++j) {
    float4 a = as4[col_src[j]];
    m0 = fmaxf(m0, lrelu(a.x + adv.x));
    m1 = fmaxf(m1, lrelu(a.y + adv.y));
    m2 = fmaxf(m2, lrelu(a.z + adv.z));
    m3 = fmaxf(m3, lrelu(a.w + adv.w));
  }
  float s0s = 0.f, s1s = 0.f, s2s = 0.f, s3s = 0.f;
  for (j = j0; j < j1; ++j) {
    float4 a = as4[col_src[j]];
    float4 ex;
    ex.x = expf(lrelu(a.x + adv.x) - m0);
    ex.y = expf(lrelu(a.y + adv.y) - m1);
    ex.z = expf(lrelu(a.z + adv.z) - m2);
    ex.w = expf(lrelu(a.w + adv.w) - m3);
    ebuf4[j] = ex;
    s0s += ex.x; s1s += ex.y; s2s += ex.z; s3s += ex.w;
  }
  float4 dn;
  dn.x = 1.f / s0s; dn.y = 1.f / s1s; dn.z = 1.f / s2s; dn.w = 1.f / s3s;
  denom4[n] = dn;
}

// --- softmax, H=1: one thread per node, unroll-4 ---
__global__ void softmax1_kernel(const int* __restrict__ row_ptr, const int* __restrict__ col_src,
                                const float* __restrict__ as, const float* __restrict__ ad,
                                float* __restrict__ ebuf, float* __restrict__ denom) {
  const int n = blockIdx.x * 256 + threadIdx.x;
  if (n >= N_NODESC) return;
  const int j0 = row_ptr[n], j1 = row_ptr[n + 1];
  const float adv = ad[n];
  float m = -INFINITY;
  int j = j0;
  for (; j + 4 <= j1; j += 4) {
    float a0 = as[col_src[j]], a1 = as[col_src[j + 1]];
    float a2 = as[col_src[j + 2]], a3 = as[col_src[j + 3]];
    m = fmaxf(m, fmaxf(fmaxf(lrelu(a0 + adv), lrelu(a1 + adv)),
                       fmaxf(lrelu(a2 + adv), lrelu(a3 + adv))));
  }
  for (; j < j1; ++j) m = fmaxf(m, lrelu(as[col_src[j]] + adv));
  float sum = 0.f;
  for (j = j0; j < j1; ++j) {
    float ex = expf(lrelu(as[col_src[j]] + adv) - m);
    ebuf[j] = ex;
    sum += ex;
  }
  denom[n] = 1.f / sum;
}

// --------- aggregation: one block per dst node, unroll-4 gather pipeline ---
template<bool ELU>
__global__ void agg_kernel(const int* __restrict__ row_ptr, const int* __restrict__ col_src,
                           const float* __restrict__ ebuf, const float* __restrict__ denom,
                           const float* __restrict__ hfeat, const float* __restrict__ b,
                           float* __restrict__ outbuf) {
  const int d = blockIdx.x;
  const int t = threadIdx.x;                       // channel h*64+c
  const int h = t >> 6;
  const int j0 = row_ptr[d], j1 = row_ptr[d + 1];
  float acc = 0.f;
  int j = j0;
  for (; j + 4 <= j1; j += 4) {
    int s0 = col_src[j],     s1 = col_src[j + 1];
    int s2 = col_src[j + 2], s3 = col_src[j + 3];
    float v0 = hfeat[(long)s0 * FC + t];
    float v1 = hfeat[(long)s1 * FC + t];
    float v2 = hfeat[(long)s2 * FC + t];
    float v3 = hfeat[(long)s3 * FC + t];
    float w0 = ebuf[(j    ) * HEADSC + h];
    float w1 = ebuf[(j + 1) * HEADSC + h];
    float w2 = ebuf[(j + 2) * HEADSC + h];
    float w3 = ebuf[(j + 3) * HEADSC + h];
    acc = fmaf(w0, v0, acc);
    acc = fmaf(w1, v1, acc);
    acc = fmaf(w2, v2, acc);
    acc = fmaf(w3, v3, acc);
  }
  for (; j < j1; ++j)
    acc = fmaf(ebuf[j * HEADSC + h], hfeat[(long)col_src[j] * FC + t], acc);
  float v = acc * denom[d * HEADSC + h] + b[t];
  if (ELU) v = v > 0.f ? v : expm1f(v);
  outbuf[(long)d * FC + t] = v;
}

// ------------- layer3 aggregation: wave per node, scalar -------------------
__global__ void agg3_kernel(const int* __restrict__ row_ptr, const int* __restrict__ col_src,
                            const float* __restrict__ ebuf, const float* __restrict__ denom,
                            const float* __restrict__ h3, const float* __restrict__ b3,
                            float* __restrict__ out) {
  const int wv = threadIdx.x >> 6;                 // 4 waves/block
  const int l  = threadIdx.x & 63;
  const int d  = blockIdx.x * 4 + wv;
  if (d >= N_NODESC) return;
  const int j0 = row_ptr[d], j1 = row_ptr[d + 1];
  float acc = 0.f;
  for (int j = j0 + l; j < j1; j += 64)
    acc = fmaf(ebuf[j], h3[col_src[j]], acc);
  for (int off = 32; off; off >>= 1) acc += __shfl_down(acc, off, 64);
  if (l == 0) out[d] = acc * denom[d] + b3[0];
}

extern "C" void kernel_launch(void* const* d_in, const int* in_sizes, int n_in,
                              void* d_out, int out_size, void* d_ws, size_t ws_size,
                              hipStream_t stream) {
  const float* x    = (const float*)d_in[0];
  const int*   ei   = (const int*)d_in[1];
  const float* W1   = (const float*)d_in[2];
  const float* as1  = (const float*)d_in[3];
  const float* ad1  = (const float*)d_in[4];
  const float* b1   = (const float*)d_in[5];
  const float* W2   = (const float*)d_in[6];
  const float* as2  = (const float*)d_in[7];
  const float* ad2  = (const float*)d_in[8];
  const float* b2   = (const float*)d_in[9];
  const float* W3   = (const float*)d_in[10];
  const float* as3  = (const float*)d_in[11];
  const float* ad3  = (const float*)d_in[12];
  const float* b3   = (const float*)d_in[13];
  float* out = (float*)d_out;

  float* ws    = (float*)d_ws;
  float* act   = ws;                              // N*256
  float* hfeat = act   + (size_t)N_NODESC * FC;   // N*256
  float* wAs   = hfeat + (size_t)N_NODESC * FC;   // N*4
  float* wAd   = wAs   + (size_t)N_NODESC * HEADSC;
  float* denom = wAd   + (size_t)N_NODESC * HEADSC;
  float* ebuf  = denom + (size_t)N_NODESC * HEADSC; // E_TOT*4
  float* h3    = ebuf  + (size_t)E_TOTC * HEADSC;   // N
  int*   ibase = (int*)(h3 + N_NODESC);
  int*   deg     = ibase;                 // N
  int*   row_ptr = deg + N_NODESC;        // N+1
  int*   cursor  = row_ptr + N_NODESC + 1;// N
  int*   col_src = cursor + N_NODESC;     // E_TOT

  const int gridE  = (E_TOTC + 255) / 256;
  const int gridN  = (N_NODESC + 255) / 256;
  const int gemmG  = N_NODESC / 32;       // 625, exact

  // ---------------- CSR build (edge_index shared by all layers) ------------
  zero_deg<<<gridN, 256, 0, stream>>>(deg);
  deg_count<<<gridE, 256, 0, stream>>>(ei, deg);
  scan_kernel<<<1, 1024, 0, stream>>>(deg, row_ptr, cursor);
  fill_kernel<<<gridE, 256, 0, stream>>>(ei, cursor, col_src);

  // ---------------- layer 1 ----------------
  gemm_kernel<128><<<gemmG, 256, 0, stream>>>(x, W1, hfeat);
  alpha_kernel<<<N_NODESC, 256, 0, stream>>>(hfeat, as1, ad1, wAs, wAd);
  softmax4_kernel<<<gridN, 256, 0, stream>>>(row_ptr, col_src, (const float4*)wAs,
                                             (const float4*)wAd, (float4*)ebuf, (float4*)denom);
  agg_kernel<true><<<N_NODESC, 256, 0, stream>>>(row_ptr, col_src, ebuf, denom, hfeat, b1, act);

  // ---------------- layer 2 ----------------
  gemm_kernel<256><<<gemmG, 256, 0, stream>>>(act, W2, hfeat);
  alpha_kernel<<<N_NODESC, 256, 0, stream>>>(hfeat, as2, ad2, wAs, wAd);
  softmax4_kernel<<<gridN, 256, 0, stream>>>(row_ptr, col_src, (const float4*)wAs,
                                             (const float4*)wAd, (float4*)ebuf, (float4*)denom);
  agg_kernel<true><<<N_NODESC, 256, 0, stream>>>(row_ptr, col_src, ebuf, denom, hfeat, b2, act);

  // ---------------- layer 3 (heads=1, out=1) ----------------
  gemm3_kernel<<<N_NODESC, 256, 0, stream>>>(act, W3, as3, ad3, h3, wAs, wAd);
  softmax1_kernel<<<gridN, 256, 0, stream>>>(row_ptr, col_src, wAs, wAd, ebuf, denom);
  agg3_kernel<<<(N_NODESC + 3) / 4, 256, 0, stream>>>(row_ptr, col_src, ebuf, denom, h3, b3, out);
}

// Round 5
// 296.891 us; speedup vs baseline: 2.9441x; 1.1973x over previous
//
#include <hip/hip_runtime.h>
#include <hip/hip_bf16.h>
#include <cmath>

#define N_NODESC 20000
#define E_RAW    320000
#define E_TOTC   340000   // + self loops
#define HEADSC   4
#define FC       256      // HEADS*HID
#define NEG_SLOPE 0.2f

__device__ __forceinline__ int dstOf(const int* ei, int e) {
  return (e < E_RAW) ? ei[E_RAW + e] : (e - E_RAW);
}
__device__ __forceinline__ int srcOf(const int* ei, int e) {
  return (e < E_RAW) ? ei[e] : (e - E_RAW);
}
__device__ __forceinline__ float lrelu(float v) { return v > 0.f ? v : NEG_SLOPE * v; }

// ---- GEMM + fused alpha: out[N,256] = A[N,K] @ W[K,256]
// 16 rows/block (1250 blocks), thread = 4 rows x 4 consecutive cols.
template<int K>
__global__ void gemm_kernel(const float* __restrict__ A, const float* __restrict__ W,
                            const float* __restrict__ a_src, const float* __restrict__ a_dst,
                            float* __restrict__ hfeat, float* __restrict__ as,
                            float* __restrict__ ad) {
  __shared__ float xs[16][K];
  const int t  = threadIdx.x;
  const int m  = t & 63;        // col group: cols 4m..4m+3
  const int rg = t >> 6;        // rows rg*4 .. rg*4+3
  const int n0 = blockIdx.x * 16;   // 20000/16 = 1250 exact
  for (int idx = t; idx < 16 * (K / 4); idx += 256) {
    int r = idx / (K / 4), c4 = idx - r * (K / 4);
    ((float4*)&xs[r][0])[c4] = ((const float4*)(A + (long)(n0 + r) * K))[c4];
  }
  __syncthreads();
  float4 acc[4];
#pragma unroll
  for (int i = 0; i < 4; ++i) acc[i] = float4{0.f, 0.f, 0.f, 0.f};
  const float* wbase = W + 4 * m;
  for (int k0 = 0; k0 < K; k0 += 4) {
    float4 w0 = *(const float4*)(wbase + (long)(k0 + 0) * FC);
    float4 w1 = *(const float4*)(wbase + (long)(k0 + 1) * FC);
    float4 w2 = *(const float4*)(wbase + (long)(k0 + 2) * FC);
    float4 w3 = *(const float4*)(wbase + (long)(k0 + 3) * FC);
#pragma unroll
    for (int i = 0; i < 4; ++i) {
      float4 a = *(const float4*)&xs[rg * 4 + i][k0];
      acc[i].x = fmaf(a.x, w0.x, acc[i].x); acc[i].y = fmaf(a.x, w0.y, acc[i].y);
      acc[i].z = fmaf(a.x, w0.z, acc[i].z); acc[i].w = fmaf(a.x, w0.w, acc[i].w);
      acc[i].x = fmaf(a.y, w1.x, acc[i].x); acc[i].y = fmaf(a.y, w1.y, acc[i].y);
      acc[i].z = fmaf(a.y, w1.z, acc[i].z); acc[i].w = fmaf(a.y, w1.w, acc[i].w);
      acc[i].x = fmaf(a.z, w2.x, acc[i].x); acc[i].y = fmaf(a.z, w2.y, acc[i].y);
      acc[i].z = fmaf(a.z, w2.z, acc[i].z); acc[i].w = fmaf(a.z, w2.w, acc[i].w);
      acc[i].x = fmaf(a.w, w3.x, acc[i].x); acc[i].y = fmaf(a.w, w3.y, acc[i].y);
      acc[i].z = fmaf(a.w, w3.z, acc[i].z); acc[i].w = fmaf(a.w, w3.w, acc[i].w);
    }
  }
  const int cc = 4 * m;
  const int h  = m >> 4;        // head of this 4-col group (never crosses 64-boundary)
  float4 asv = *(const float4*)(a_src + cc);
  float4 adv = *(const float4*)(a_dst + cc);
#pragma unroll
  for (int i = 0; i < 4; ++i) {
    int n = n0 + rg * 4 + i;
    *(float4*)(hfeat + (long)n * FC + cc) = acc[i];
    float ps = acc[i].x * asv.x + acc[i].y * asv.y + acc[i].z * asv.z + acc[i].w * asv.w;
    float pd = acc[i].x * adv.x + acc[i].y * adv.y + acc[i].z * adv.z + acc[i].w * adv.w;
    for (int off = 8; off; off >>= 1) {
      ps += __shfl_down(ps, off, 16);
      pd += __shfl_down(pd, off, 16);
    }
    if ((m & 15) == 0) {
      as[n * HEADSC + h] = ps;
      ad[n * HEADSC + h] = pd;
    }
  }
}

// ------------- layer3 projection: h3[n] = act[n,:] . W3, + alphas ----------
__global__ void gemm3_kernel(const float* __restrict__ A, const float* __restrict__ W3,
                             const float* __restrict__ asc, const float* __restrict__ adc,
                             float* __restrict__ h3, float* __restrict__ as,
                             float* __restrict__ ad) {
  const int n = blockIdx.x;
  const int t = threadIdx.x;            // 256
  float v = A[(long)n * FC + t] * W3[t];
  for (int off = 32; off; off >>= 1) v += __shfl_down(v, off, 64);
  __shared__ float red[4];
  if ((t & 63) == 0) red[t >> 6] = v;
  __syncthreads();
  if (t == 0) {
    float s = red[0] + red[1] + red[2] + red[3];
    h3[n] = s;
    as[n] = s * asc[0];
    ad[n] = s * adc[0];
  }
}

// ----------------------------- CSR build -----------------------------------
__global__ void zero_deg(int* __restrict__ deg) {
  int i = blockIdx.x * 256 + threadIdx.x;
  if (i < N_NODESC) deg[i] = 0;
}

__global__ void deg_count(const int* __restrict__ ei, int* __restrict__ deg) {
  int e = blockIdx.x * 256 + threadIdx.x;
  if (e >= E_TOTC) return;
  atomicAdd(&deg[dstOf(ei, e)], 1);
}

__global__ void scan_kernel(const int* __restrict__ deg, int* __restrict__ row_ptr,
                            int* __restrict__ cursor) {
  __shared__ int partial[1024];
  const int t = threadIdx.x;                       // 1024 threads, single block
  const int PER = (N_NODESC + 1023) / 1024;        // 20
  const int base = t * PER;
  int s = 0;
  for (int i = 0; i < PER; ++i) {
    int idx = base + i;
    if (idx < N_NODESC) s += deg[idx];
  }
  partial[t] = s;
  __syncthreads();
  for (int off = 1; off < 1024; off <<= 1) {
    int v = (t >= off) ? partial[t - off] : 0;
    __syncthreads();
    partial[t] += v;
    __syncthreads();
  }
  int run = (t == 0) ? 0 : partial[t - 1];
  for (int i = 0; i < PER; ++i) {
    int idx = base + i;
    if (idx < N_NODESC) {
      row_ptr[idx] = run;
      cursor[idx]  = run;
      run += deg[idx];
    }
  }
  if (t == 1023) row_ptr[N_NODESC] = run;          // = E_TOTC
}

__global__ void fill_kernel(const int* __restrict__ ei, int* __restrict__ cursor,
                            int* __restrict__ col_src) {
  int e = blockIdx.x * 256 + threadIdx.x;
  if (e >= E_TOTC) return;
  int d = dstOf(ei, e);
  int pos = atomicAdd(&cursor[d], 1);
  col_src[pos] = srcOf(ei, e);
}

// --- softmax, H=4: one WAVE per node; lanes stride edges; xor-shuffle reduce
__global__ void softmax4_kernel(const int* __restrict__ row_ptr, const int* __restrict__ col_src,
                                const float4* __restrict__ as4, const float4* __restrict__ ad4,
                                float4* __restrict__ ebuf4, float4* __restrict__ denom4) {
  const int w = threadIdx.x >> 6, l = threadIdx.x & 63;
  const int n = blockIdx.x * 4 + w;
  if (n >= N_NODESC) return;
  const int j0 = row_ptr[n], j1 = row_ptr[n + 1];
  const float4 adv = ad4[n];
  float4 mx = float4{-INFINITY, -INFINITY, -INFINITY, -INFINITY};
  for (int j = j0 + l; j < j1; j += 64) {
    float4 a = as4[col_src[j]];
    float4 v;
    v.x = lrelu(a.x + adv.x); v.y = lrelu(a.y + adv.y);
    v.z = lrelu(a.z + adv.z); v.w = lrelu(a.w + adv.w);
    ebuf4[j] = v;
    mx.x = fmaxf(mx.x, v.x); mx.y = fmaxf(mx.y, v.y);
    mx.z = fmaxf(mx.z, v.z); mx.w = fmaxf(mx.w, v.w);
  }
  for (int off = 32; off; off >>= 1) {
    mx.x = fmaxf(mx.x, __shfl_xor(mx.x, off, 64));
    mx.y = fmaxf(mx.y, __shfl_xor(mx.y, off, 64));
    mx.z = fmaxf(mx.z, __shfl_xor(mx.z, off, 64));
    mx.w = fmaxf(mx.w, __shfl_xor(mx.w, off, 64));
  }
  float4 sm = float4{0.f, 0.f, 0.f, 0.f};
  for (int j = j0 + l; j < j1; j += 64) {
    float4 v = ebuf4[j];
    float4 e;
    e.x = expf(v.x - mx.x); e.y = expf(v.y - mx.y);
    e.z = expf(v.z - mx.z); e.w = expf(v.w - mx.w);
    ebuf4[j] = e;
    sm.x += e.x; sm.y += e.y; sm.z += e.z; sm.w += e.w;
  }
  for (int off = 32; off; off >>= 1) {
    sm.x += __shfl_xor(sm.x, off, 64);
    sm.y += __shfl_xor(sm.y, off, 64);
    sm.z += __shfl_xor(sm.z, off, 64);
    sm.w += __shfl_xor(sm.w, off, 64);
  }
  if (l == 0)
    denom4[n] = float4{1.f / sm.x, 1.f / sm.y, 1.f / sm.z, 1.f / sm.w};
}

// --- softmax, H=1: one wave per node ---
__global__ void softmax1_kernel(const int* __restrict__ row_ptr, const int* __restrict__ col_src,
                                const float* __restrict__ as, const float* __restrict__ ad,
                                float* __restrict__ ebuf, float* __restrict__ denom) {
  const int w = threadIdx.x >> 6, l = threadIdx.x & 63;
  const int n = blockIdx.x * 4 + w;
  if (n >= N_NODESC) return;
  const int j0 = row_ptr[n], j1 = row_ptr[n + 1];
  const float adv = ad[n];
  float mx = -INFINITY;
  for (int j = j0 + l; j < j1; j += 64) {
    float v = lrelu(as[col_src[j]] + adv);
    ebuf[j] = v;
    mx = fmaxf(mx, v);
  }
  for (int off = 32; off; off >>= 1) mx = fmaxf(mx, __shfl_xor(mx, off, 64));
  float sm = 0.f;
  for (int j = j0 + l; j < j1; j += 64) {
    float e = expf(ebuf[j] - mx);
    ebuf[j] = e;
    sm += e;
  }
  for (int off = 32; off; off >>= 1) sm += __shfl_xor(sm, off, 64);
  if (l == 0) denom[n] = 1.f / sm;
}

// --------- aggregation: one block per dst node, unroll-8 gather pipeline ---
template<bool ELU>
__global__ void agg_kernel(const int* __restrict__ row_ptr, const int* __restrict__ col_src,
                           const float* __restrict__ ebuf, const float* __restrict__ denom,
                           const float* __restrict__ hfeat, const float* __restrict__ b,
                           float* __restrict__ outbuf) {
  const int d = blockIdx.x;
  const int t = threadIdx.x;                       // channel h*64+c
  const int h = t >> 6;
  const int j0 = row_ptr[d], j1 = row_ptr[d + 1];
  float acc = 0.f;
  int j = j0;
  for (; j + 8 <= j1; j += 8) {
    int   s[8];
    float v[8], w[8];
#pragma unroll
    for (int u = 0; u < 8; ++u) s[u] = col_src[j + u];
#pragma unroll
    for (int u = 0; u < 8; ++u) v[u] = hfeat[(long)s[u] * FC + t];
#pragma unroll
    for (int u = 0; u < 8; ++u) w[u] = ebuf[(j + u) * HEADSC + h];
#pragma unroll
    for (int u = 0; u < 8; ++u) acc = fmaf(w[u], v[u], acc);
  }
  for (; j + 4 <= j1; j += 4) {
    int s0 = col_src[j],     s1 = col_src[j + 1];
    int s2 = col_src[j + 2], s3 = col_src[j + 3];
    float v0 = hfeat[(long)s0 * FC + t];
    float v1 = hfeat[(long)s1 * FC + t];
    float v2 = hfeat[(long)s2 * FC + t];
    float v3 = hfeat[(long)s3 * FC + t];
    acc = fmaf(ebuf[(j    ) * HEADSC + h], v0, acc);
    acc = fmaf(ebuf[(j + 1) * HEADSC + h], v1, acc);
    acc = fmaf(ebuf[(j + 2) * HEADSC + h], v2, acc);
    acc = fmaf(ebuf[(j + 3) * HEADSC + h], v3, acc);
  }
  for (; j < j1; ++j)
    acc = fmaf(ebuf[j * HEADSC + h], hfeat[(long)col_src[j] * FC + t], acc);
  float v = acc * denom[d * HEADSC + h] + b[t];
  if (ELU) v = v > 0.f ? v : expm1f(v);
  outbuf[(long)d * FC + t] = v;
}

// ------------- layer3 aggregation: wave per node, scalar -------------------
__global__ void agg3_kernel(const int* __restrict__ row_ptr, const int* __restrict__ col_src,
                            const float* __restrict__ ebuf, const float* __restrict__ denom,
                            const float* __restrict__ h3, const float* __restrict__ b3,
                            float* __restrict__ out) {
  const int wv = threadIdx.x >> 6;                 // 4 waves/block
  const int l  = threadIdx.x & 63;
  const int d  = blockIdx.x * 4 + wv;
  if (d >= N_NODESC) return;
  const int j0 = row_ptr[d], j1 = row_ptr[d + 1];
  float acc = 0.f;
  for (int j = j0 + l; j < j1; j += 64)
    acc = fmaf(ebuf[j], h3[col_src[j]], acc);
  for (int off = 32; off; off >>= 1) acc += __shfl_down(acc, off, 64);
  if (l == 0) out[d] = acc * denom[d] + b3[0];
}

extern "C" void kernel_launch(void* const* d_in, const int* in_sizes, int n_in,
                              void* d_out, int out_size, void* d_ws, size_t ws_size,
                              hipStream_t stream) {
  const float* x    = (const float*)d_in[0];
  const int*   ei   = (const int*)d_in[1];
  const float* W1   = (const float*)d_in[2];
  const float* as1  = (const float*)d_in[3];
  const float* ad1  = (const float*)d_in[4];
  const float* b1   = (const float*)d_in[5];
  const float* W2   = (const float*)d_in[6];
  const float* as2  = (const float*)d_in[7];
  const float* ad2  = (const float*)d_in[8];
  const float* b2   = (const float*)d_in[9];
  const float* W3   = (const float*)d_in[10];
  const float* as3  = (const float*)d_in[11];
  const float* ad3  = (const float*)d_in[12];
  const float* b3   = (const float*)d_in[13];
  float* out = (float*)d_out;

  float* ws    = (float*)d_ws;
  float* act   = ws;                              // N*256
  float* hfeat = act   + (size_t)N_NODESC * FC;   // N*256
  float* wAs   = hfeat + (size_t)N_NODESC * FC;   // N*4
  float* wAd   = wAs   + (size_t)N_NODESC * HEADSC;
  float* denom = wAd   + (size_t)N_NODESC * HEADSC;
  float* ebuf  = denom + (size_t)N_NODESC * HEADSC; // E_TOT*4
  float* h3    = ebuf  + (size_t)E_TOTC * HEADSC;   // N
  int*   ibase = (int*)(h3 + N_NODESC);
  int*   deg     = ibase;                 // N
  int*   row_ptr = deg + N_NODESC;        // N+1
  int*   cursor  = row_ptr + N_NODESC + 1;// N
  int*   col_src = cursor + N_NODESC;     // E_TOT

  const int gridE  = (E_TOTC + 255) / 256;
  const int gridN  = (N_NODESC + 255) / 256;
  const int gridN4 = (N_NODESC + 3) / 4;
  const int gemmG  = N_NODESC / 16;       // 1250, exact

  // ---------------- CSR build (edge_index shared by all layers) ------------
  zero_deg<<<gridN, 256, 0, stream>>>(deg);
  deg_count<<<gridE, 256, 0, stream>>>(ei, deg);
  scan_kernel<<<1, 1024, 0, stream>>>(deg, row_ptr, cursor);
  fill_kernel<<<gridE, 256, 0, stream>>>(ei, cursor, col_src);

  // ---------------- layer 1 ----------------
  gemm_kernel<128><<<gemmG, 256, 0, stream>>>(x, W1, as1, ad1, hfeat, wAs, wAd);
  softmax4_kernel<<<gridN4, 256, 0, stream>>>(row_ptr, col_src, (const float4*)wAs,
                                              (const float4*)wAd, (float4*)ebuf, (float4*)denom);
  agg_kernel<true><<<N_NODESC, 256, 0, stream>>>(row_ptr, col_src, ebuf, denom, hfeat, b1, act);

  // ---------------- layer 2 ----------------
  gemm_kernel<256><<<gemmG, 256, 0, stream>>>(act, W2, as2, ad2, hfeat, wAs, wAd);
  softmax4_kernel<<<gridN4, 256, 0, stream>>>(row_ptr, col_src, (const float4*)wAs,
                                              (const float4*)wAd, (float4*)ebuf, (float4*)denom);
  agg_kernel<true><<<N_NODESC, 256, 0, stream>>>(row_ptr, col_src, ebuf, denom, hfeat, b2, act);

  // ---------------- layer 3 (heads=1, out=1) ----------------
  gemm3_kernel<<<N_NODESC, 256, 0, stream>>>(act, W3, as3, ad3, h3, wAs, wAd);
  softmax1_kernel<<<gridN4, 256, 0, stream>>>(row_ptr, col_src, wAs, wAd, ebuf, denom);
  agg3_kernel<<<gridN4, 256, 0, stream>>>(row_ptr, col_src, ebuf, denom, h3, b3, out);
}